// Round 3
// baseline (208.615 us; speedup 1.0000x reference)
//
#include <hip/hip_runtime.h>

// VectorQuantizer: x [16,1024,256] f32, E [8192,256] f32.
// Outputs concat: quantized_st (4194304 f32) | loss (1) | perplexity (1).
//
// Round 12: TLP via code-split blocks, NOT bigger blocks. r10/r11 evidence:
// 1024-thread blocks force a 64-arch-VGPR split on the unified file ->
// scratch spill (+29 MB WRITE, MfmaUtil DOWN). r9's 256-thread shape
// (VGPR 128, no scratch) is the known-good codegen -> keep it verbatim and
// split the CODE dimension 4 ways across blocks instead. Grid 1024
// (slice-major): block = (slice = bid>>8, rowgroup = bid&255), scores
// 64 rows x 2048 codes (32 steps/wave, same depth-4 pipeline). Per-row
// (score,idx) candidates go to workspace; last-of-4 sibling (rowticket)
// merges lexicographically (exact same argmin/tie semantics) and runs the
// unchanged gather+loss+hist+finalize epilogue. Ebs L2 floor unchanged
// (1024 x 0.5 MB = 512 MB); 4 blocks/CU -> 4 waves/SIMD of independent
// MFMA streams where r9 had 1.

#define VQ_N 16384
#define VQ_D 256
#define VQ_K 8192

typedef __attribute__((ext_vector_type(4))) int i32x4;

#define SX 22.0f
#define SEF 1040384.0f               // 127 * 8192
#define ENSCALE 11444224.0           // SX * SEF / 2

__device__ inline int q8(float f, float scale) {
  return __float2int_rn(fminf(fmaxf(f * scale, -127.f), 127.f));
}

// ---- pack E -> i8 swizzled + en_int + zero hist/tickets/loss ----
// Main-kernel B addr: g*4096 + (m*4+quad)*256 + c15*16 + j; code = g*16+c15,
// k = (m*4+quad)*16 + j. Pack thread = (code, chunk), chunk = m*4+quad.
__global__ __launch_bounds__(256) void vq_pack(
    const float* __restrict__ E, signed char* __restrict__ Ebs,
    int* __restrict__ en_int, double* __restrict__ loss_sum,
    int* __restrict__ hist, unsigned int* __restrict__ ticket,
    unsigned int* __restrict__ rowticket) {
  const int gid = blockIdx.x * 256 + threadIdx.x;  // 0..131071
  if (gid < VQ_K) hist[gid] = 0;
  if (gid < 256) rowticket[gid] = 0u;
  if (gid == 0) { *loss_sum = 0.0; *ticket = 0u; }
  const int code = gid >> 4;
  const int chunk = gid & 15;
  const float* src = E + (size_t)code * VQ_D + chunk * 16;
  double s = 0.0;
  unsigned int w[4];
#pragma unroll
  for (int v = 0; v < 4; ++v) {
    const float4 f = *(const float4*)(src + v * 4);
    s += (double)f.x * f.x + (double)f.y * f.y + (double)f.z * f.z +
         (double)f.w * f.w;
    const int q0 = q8(f.x, SEF), q1 = q8(f.y, SEF);
    const int q2 = q8(f.z, SEF), q3 = q8(f.w, SEF);
    w[v] = (unsigned)(q0 & 255) | ((unsigned)(q1 & 255) << 8) |
           ((unsigned)(q2 & 255) << 16) | ((unsigned)(q3 & 255) << 24);
  }
  const size_t off =
      ((size_t)(code >> 4) * 16 + chunk) * 256 + (size_t)(code & 15) * 16;
  *(uint4*)(Ebs + off) = make_uint4(w[0], w[1], w[2], w[3]);
  // ||e||^2 over the 16 lanes sharing `code` (chunk == lane&15)
#pragma unroll
  for (int m = 1; m <= 8; m <<= 1) s += __shfl_xor(s, m, 64);
  if (chunk == 0) en_int[code] = (int)__double2int_rn(s * ENSCALE);
}

// ---- fused i8 score (1/4 of codes) + candidate write + merge epilogue ----
// Grid 1024 x 256. Block: 64 rows x 2048 codes. Wave w owns 16-code groups
// g = slice*128 + w + 4*i (i 0..31, ascending). Depth-4 register pipeline.
__global__ __launch_bounds__(256, 1) void vq_main(
    const float* __restrict__ X, const signed char* __restrict__ Ebs,
    const int* __restrict__ en_int, const float* __restrict__ Ef,
    float* __restrict__ outq, double* __restrict__ loss_sum,
    int* __restrict__ hist, unsigned int* __restrict__ ticket,
    unsigned int* __restrict__ rowticket, int* __restrict__ cand_s,
    int* __restrict__ cand_i, float* __restrict__ out) {
  __shared__ int red_s[4][64];
  __shared__ int red_i[4][64];
  __shared__ int kfin[64];
  __shared__ double wsum[4];
  __shared__ double part[256];
  __shared__ int smerge;
  __shared__ int sdone;

  const int tid = threadIdx.x;
  const int wave = tid >> 6;
  const int lane = tid & 63;
  const int quad = lane >> 4;
  const int c15 = lane & 15;
  const int rg = blockIdx.x & 255;    // row-group
  const int slice = blockIdx.x >> 8;  // code slice 0..3
  const int r0 = rg * 64;

  // A fragments: af[t][m], row r0+t*16+c15, bytes j -> k = m*64+quad*16+j.
  i32x4 af[4][4];
#pragma unroll
  for (int t = 0; t < 4; ++t) {
    const float* xr = X + (size_t)(r0 + t * 16 + c15) * VQ_D + quad * 16;
#pragma unroll
    for (int m = 0; m < 4; ++m) {
      const float* p = xr + m * 64;
      i32x4 pk;
#pragma unroll
      for (int v = 0; v < 4; ++v) {
        const float4 f = *(const float4*)(p + v * 4);
        const int q0 = q8(f.x, SX), q1 = q8(f.y, SX);
        const int q2 = q8(f.z, SX), q3 = q8(f.w, SX);
        pk[v] = (q0 & 255) | ((q1 & 255) << 8) | ((q2 & 255) << 16) |
                ((q3 & 255) << 24);
      }
      af[t][m] = pk;
    }
  }

  int best_s[4][4];
  int best_i[4][4];
#pragma unroll
  for (int t = 0; t < 4; ++t)
#pragma unroll
    for (int r = 0; r < 4; ++r) { best_s[t][r] = 0x7fffffff; best_i[t][r] = 0; }

  // Load cursor (advances 4 groups = 16384 B per LOADB); compute cursor codes.
  const signed char* bp = Ebs + (size_t)slice * 524288 +
                          (size_t)wave * 4096 + (size_t)quad * 256 +
                          (size_t)c15 * 16;
  const int* enp = en_int + slice * 2048 + wave * 16 + c15;
  int lidx = 0;                             // load group-step
  int ccode = slice * 2048 + wave * 16 + c15;  // compute code cursor (+64/step)

#define LOADB(buf, en)                                                       \
  {                                                                          \
    const signed char* p_ = bp + (size_t)lidx * 16384;                       \
    _Pragma("unroll") for (int m = 0; m < 4; ++m)                            \
        buf[m] = *(const i32x4*)(p_ + m * 1024);                             \
    en = enp[lidx * 64];                                                     \
    ++lidx;                                                                  \
  }

#define COMPUTE(buf, en)                                                     \
  {                                                                          \
    i32x4 a0 = {0, 0, 0, 0}, a1 = {0, 0, 0, 0};                              \
    i32x4 a2 = {0, 0, 0, 0}, a3 = {0, 0, 0, 0};                              \
    _Pragma("unroll") for (int m = 0; m < 4; ++m) {                          \
      a0 = __builtin_amdgcn_mfma_i32_16x16x64_i8(af[0][m], buf[m], a0, 0, 0, 0); \
      a1 = __builtin_amdgcn_mfma_i32_16x16x64_i8(af[1][m], buf[m], a1, 0, 0, 0); \
      a2 = __builtin_amdgcn_mfma_i32_16x16x64_i8(af[2][m], buf[m], a2, 0, 0, 0); \
      a3 = __builtin_amdgcn_mfma_i32_16x16x64_i8(af[3][m], buf[m], a3, 0, 0, 0); \
    }                                                                        \
    _Pragma("unroll") for (int r = 0; r < 4; ++r) {                          \
      int s;                                                                 \
      s = en - a0[r];                                                        \
      if (s < best_s[0][r]) { best_s[0][r] = s; best_i[0][r] = ccode; }      \
      s = en - a1[r];                                                        \
      if (s < best_s[1][r]) { best_s[1][r] = s; best_i[1][r] = ccode; }      \
      s = en - a2[r];                                                        \
      if (s < best_s[2][r]) { best_s[2][r] = s; best_i[2][r] = ccode; }      \
      s = en - a3[r];                                                        \
      if (s < best_s[3][r]) { best_s[3][r] = s; best_i[3][r] = ccode; }      \
    }                                                                        \
    ccode += 64;                                                             \
  }

  i32x4 bb0[4], bb1[4], bb2[4], bb3[4];
  int en0, en1, en2, en3;
  LOADB(bb0, en0); LOADB(bb1, en1); LOADB(bb2, en2); LOADB(bb3, en3);
#pragma unroll 1
  for (int i = 0; i < 28; i += 4) {  // compute i..i+3, load i+4..i+7
    COMPUTE(bb0, en0); LOADB(bb0, en0);
    COMPUTE(bb1, en1); LOADB(bb1, en1);
    COMPUTE(bb2, en2); LOADB(bb2, en2);
    COMPUTE(bb3, en3); LOADB(bb3, en3);
  }
  COMPUTE(bb0, en0); COMPUTE(bb1, en1); COMPUTE(bb2, en2); COMPUTE(bb3, en3);
#undef LOADB
#undef COMPUTE

  // reduce over the 16 code-lanes (c15 bits), lowest index on ties
#pragma unroll
  for (int t = 0; t < 4; ++t)
#pragma unroll
    for (int r = 0; r < 4; ++r) {
      int s = best_s[t][r];
      int i = best_i[t][r];
#pragma unroll
      for (int m = 1; m <= 8; m <<= 1) {
        const int os = __shfl_xor(s, m, 64);
        const int oi = __shfl_xor(i, m, 64);
        if (os < s || (os == s && oi < i)) { s = os; i = oi; }
      }
      if (c15 == 0) {
        red_s[wave][t * 16 + quad * 4 + r] = s;
        red_i[wave][t * 16 + quad * 4 + r] = i;
      }
    }
  __syncthreads();

  // cross-wave merge -> this block's candidate per row -> workspace
  if (tid < 64) {
    int bs = red_s[0][tid];
    int bi = red_i[0][tid];
#pragma unroll
    for (int w = 1; w < 4; ++w) {
      const int s = red_s[w][tid];
      const int i = red_i[w][tid];
      if (s < bs || (s == bs && i < bi)) { bs = s; bi = i; }
    }
    cand_s[rg * 256 + slice * 64 + tid] = bs;
    cand_i[rg * 256 + slice * 64 + tid] = bi;
  }
  __syncthreads();  // drains vmcnt: all cand stores at L2 before the ticket
  if (tid == 0) {
    __threadfence();
    const unsigned int old = __hip_atomic_fetch_add(
        &rowticket[rg], 1u, __ATOMIC_ACQ_REL, __HIP_MEMORY_SCOPE_AGENT);
    smerge = (old == 3u) ? 1 : 0;
  }
  __syncthreads();
  if (!smerge) return;  // 3 of 4 sibling blocks are done

  // last sibling: merge 4 slices lexicographically -> final index; hist
  if (tid < 64) {
    int bs = cand_s[rg * 256 + tid];
    int bi = cand_i[rg * 256 + tid];
#pragma unroll
    for (int s4 = 1; s4 < 4; ++s4) {
      const int s = cand_s[rg * 256 + s4 * 64 + tid];
      const int i = cand_i[rg * 256 + s4 * 64 + tid];
      if (s < bs || (s == bs && i < bi)) { bs = s; bi = i; }
    }
    kfin[tid] = bi;
    __hip_atomic_fetch_add(&hist[bi], 1, __ATOMIC_RELAXED,
                           __HIP_MEMORY_SCOPE_AGENT);
  }
  __syncthreads();

  // fused gather (from f32 E) + loss partial: wave w handles rows w*16..+16
  double lacc = 0.0;
#pragma unroll
  for (int j = 0; j < 16; ++j) {
    const int rl = wave * 16 + j;
    const int k = kfin[rl];
    const float4 q = *(const float4*)(Ef + (size_t)k * VQ_D + lane * 4);
    const float4 x =
        *(const float4*)(X + (size_t)(r0 + rl) * VQ_D + lane * 4);
    *(float4*)(outq + (size_t)(r0 + rl) * VQ_D + lane * 4) = q;
    const double dx = (double)q.x - x.x, dy = (double)q.y - x.y;
    const double dz = (double)q.z - x.z, dw = (double)q.w - x.w;
    lacc += dx * dx + dy * dy + dz * dz + dw * dw;
  }
#pragma unroll
  for (int off = 32; off > 0; off >>= 1) lacc += __shfl_down(lacc, off, 64);
  if (lane == 0) wsum[wave] = lacc;
  __syncthreads();
  if (tid == 0) {
    atomicAdd(loss_sum, wsum[0] + wsum[1] + wsum[2] + wsum[3]);
    __threadfence();
    const unsigned int old = __hip_atomic_fetch_add(
        ticket, 1u, __ATOMIC_ACQ_REL, __HIP_MEMORY_SCOPE_AGENT);
    sdone = (old == 255u) ? 1 : 0;
  }
  __syncthreads();

  if (sdone) {  // last merger: all hist/loss atomics are visible
    double s = 0.0;
    for (int k = tid; k < VQ_K; k += 256) {
      const int c = __hip_atomic_load(&hist[k], __ATOMIC_RELAXED,
                                      __HIP_MEMORY_SCOPE_AGENT);
      if (c > 0) {
        const double pr = (double)c * (1.0 / (double)VQ_N);
        s += pr * log(pr + 1e-10);
      }
    }
    part[tid] = s;
    __syncthreads();
    for (int off = 128; off > 0; off >>= 1) {
      if (tid < off) part[tid] += part[tid + off];
      __syncthreads();
    }
    if (tid == 0) {
      const double ls = __hip_atomic_load(loss_sum, __ATOMIC_RELAXED,
                                          __HIP_MEMORY_SCOPE_AGENT);
      out[(size_t)VQ_N * VQ_D] =
          (float)(1.25 * ls / ((double)VQ_N * (double)VQ_D));
      out[(size_t)VQ_N * VQ_D + 1] = (float)exp(-part[0]);
    }
  }
}

extern "C" void kernel_launch(void* const* d_in, const int* in_sizes, int n_in,
                              void* d_out, int out_size, void* d_ws,
                              size_t ws_size, hipStream_t stream) {
  const float* X = (const float*)d_in[0];
  const float* E = (const float*)d_in[1];
  float* out = (float*)d_out;

  char* ws = (char*)d_ws;
  signed char* Ebs = (signed char*)ws;                       // 2 MB
  int* en_int = (int*)(ws + 2097152);                        // 32 KB
  double* loss_sum = (double*)(ws + 2129920);                // 64 B
  int* hist = (int*)(ws + 2129984);                          // 32 KB
  unsigned int* ticket = (unsigned int*)(ws + 2162752);      // 64 B
  unsigned int* rowticket = (unsigned int*)(ws + 2162816);   // 1 KB
  int* cand_s = (int*)(ws + 2163840);                        // 256 KB
  int* cand_i = (int*)(ws + 2425984);                        // 256 KB

  vq_pack<<<512, 256, 0, stream>>>(E, Ebs, en_int, loss_sum, hist, ticket,
                                   rowticket);
  vq_main<<<1024, 256, 0, stream>>>(X, Ebs, en_int, E, out, loss_sum, hist,
                                    ticket, rowticket, cand_s, cand_i, out);
}

// Round 4
// 177.941 us; speedup vs baseline: 1.1724x; 1.1724x over previous
//
#include <hip/hip_runtime.h>

// VectorQuantizer: x [16,1024,256] f32, E [8192,256] f32.
// Outputs concat: quantized_st (4194304 f32) | loss (1) | perplexity (1).
//
// Round 13: LDS-resident-B GEMM restructure. r9/r12 evidence: MFMA-busy is
// pinned at ~13.5us (~= the 17us i8-MFMA floor) while wall is 97-145us; the
// loop's B operands stream from GLOBAL via flat loads -> per-step exposed L2
// latency + address VALU (VALUBusy > MfmaUtil). Fix the structure:
//   pack: E->i8 (as before) AND X->Xq i8 (4 MB) in fragment-linear layout
//         (kills in-loop quant + X re-reads).
//   main: grid 256 = 16 rowgroups x 16 code-slices. Block stages its 512-code
//         slice in LDS ONCE (128 KB) + en-keys (2 KB); each wave streams 256
//         rows: per 64-row round, 16 global b128 A-loads, then 32 groups of
//         {4 ds_read_b128 (depth-2) + 16 MFMA + packed-key argmin}. No
//         barriers in loop, no per-step global loads. LDS feed 6.8us/block <
//         MFMA 17.4us -> MFMA-bound by construction.
//   epi:  merge 16 int64-packed (s,i) slice-candidates per row (lexicographic
//         min == r9 tie-break), then the proven gather/loss/hist/perplexity.
// Integer scores bit-identical to r9 -> same outputs.

#define VQ_N 16384
#define VQ_D 256
#define VQ_K 8192

typedef __attribute__((ext_vector_type(4))) int i32x4;

#define SX 22.0f
#define SEF 1040384.0f               // 127 * 8192
#define ENSCALE 11444224.0           // SX * SEF / 2

__device__ inline int q8(float f, float scale) {
  return __float2int_rn(fminf(fmaxf(f * scale, -127.f), 127.f));
}

// ---- pack E -> i8 swizzled + en_int, X -> Xq i8 (same tile layout),
//      zero hist/ticket/loss ----
// Tile layout (16 rows x 256 B): off = tile*4096 + chunk*256 + (row&15)*16,
// chunk = m*4+quad. Matches main-kernel fragment reads at
// tile*4096 + m*1024 + lane*16 (lane = quad*16+c15).
__global__ __launch_bounds__(256) void vq_pack(
    const float* __restrict__ E, const float* __restrict__ X,
    signed char* __restrict__ Ebs, signed char* __restrict__ Xq,
    int* __restrict__ en_int, double* __restrict__ loss_sum,
    int* __restrict__ hist, unsigned int* __restrict__ ticket) {
  const int gid = blockIdx.x * 256 + threadIdx.x;  // 0..393215
  if (gid < VQ_K) hist[gid] = 0;
  if (gid == 0) { *loss_sum = 0.0; *ticket = 0u; }
  if (gid < 131072) {  // blocks 0..511: E pack (wave-uniform branch)
    const int code = gid >> 4;
    const int chunk = gid & 15;
    const float* src = E + (size_t)code * VQ_D + chunk * 16;
    double s = 0.0;
    unsigned int w[4];
#pragma unroll
    for (int v = 0; v < 4; ++v) {
      const float4 f = *(const float4*)(src + v * 4);
      s += (double)f.x * f.x + (double)f.y * f.y + (double)f.z * f.z +
           (double)f.w * f.w;
      const int q0 = q8(f.x, SEF), q1 = q8(f.y, SEF);
      const int q2 = q8(f.z, SEF), q3 = q8(f.w, SEF);
      w[v] = (unsigned)(q0 & 255) | ((unsigned)(q1 & 255) << 8) |
             ((unsigned)(q2 & 255) << 16) | ((unsigned)(q3 & 255) << 24);
    }
    const size_t off =
        ((size_t)(code >> 4) * 16 + chunk) * 256 + (size_t)(code & 15) * 16;
    *(uint4*)(Ebs + off) = make_uint4(w[0], w[1], w[2], w[3]);
    // ||e||^2 over the 16 lanes sharing `code` (chunk == lane&15)
#pragma unroll
    for (int m = 1; m <= 8; m <<= 1) s += __shfl_xor(s, m, 64);
    if (chunk == 0) en_int[code] = (int)__double2int_rn(s * ENSCALE);
  } else {  // blocks 512..1535: X pack
    const int xid = gid - 131072;  // 0..262143
    const int row = xid >> 4;
    const int chunk = xid & 15;
    const float* src = X + (size_t)row * VQ_D + chunk * 16;
    unsigned int w[4];
#pragma unroll
    for (int v = 0; v < 4; ++v) {
      const float4 f = *(const float4*)(src + v * 4);
      const int q0 = q8(f.x, SX), q1 = q8(f.y, SX);
      const int q2 = q8(f.z, SX), q3 = q8(f.w, SX);
      w[v] = (unsigned)(q0 & 255) | ((unsigned)(q1 & 255) << 8) |
             ((unsigned)(q2 & 255) << 16) | ((unsigned)(q3 & 255) << 24);
    }
    const size_t off =
        ((size_t)(row >> 4) * 16 + chunk) * 256 + (size_t)(row & 15) * 16;
    *(uint4*)(Xq + off) = make_uint4(w[0], w[1], w[2], w[3]);
  }
}

// ---- LDS-resident-B scorer: 16 rowgroups x 16 slices ----
// Block: 1024 rows x 512 codes. B slice (128 KB) + en (2 KB) staged once.
// Wave w streams rows [rg*1024 + w*256 .. +256) in 4 rounds of 64 rows.
__global__ __launch_bounds__(256, 1) void vq_main(
    const signed char* __restrict__ Ebs, const signed char* __restrict__ Xq,
    const int* __restrict__ en_int, long long* __restrict__ cand) {
  __shared__ __align__(16) signed char Blds[131072];
  __shared__ int ens[512];

  const int tid = threadIdx.x;
  const int wave = tid >> 6;
  const int lane = tid & 63;
  const int quad = lane >> 4;
  const int c15 = lane & 15;
  const int rg = blockIdx.x & 15;
  const int slice = blockIdx.x >> 4;

  // stage B slice + en-keys
  {
    const signed char* src = Ebs + (size_t)slice * 131072;
#pragma unroll 4
    for (int it = 0; it < 32; ++it) {
      const int off = it * 4096 + tid * 16;
      *(i32x4*)(Blds + off) = *(const i32x4*)(src + off);
    }
    if (tid < 128) {
      const int4 e4 = *(const int4*)(en_int + slice * 512 + tid * 4);
      *(int4*)(ens + tid * 4) = e4;
    }
  }
  __syncthreads();

  const int wrow0 = rg * 1024 + wave * 256;

#pragma unroll 1
  for (int rr = 0; rr < 4; ++rr) {
    // A fragments for 64 rows: af[t][m], row = base + t*16 + c15,
    // k = m*64 + quad*16 + j  (direct b128 from fragment-linear Xq).
    const signed char* ap = Xq + (size_t)(wrow0 + rr * 64) * 256;
    i32x4 af[4][4];
#pragma unroll
    for (int t = 0; t < 4; ++t)
#pragma unroll
      for (int m = 0; m < 4; ++m)
        af[t][m] = *(const i32x4*)(ap + t * 4096 + m * 1024 + lane * 16);

    // Packed argmin key: ((en - dot) << 8) | g. |en-dot| < 2^23, g < 32 ->
    // int min == lexicographic (score, g); lower g == lower code per lane.
    int best[4][4];
#pragma unroll
    for (int t = 0; t < 4; ++t)
#pragma unroll
      for (int r = 0; r < 4; ++r) best[t][r] = 0x7fffffff;

    i32x4 bfA[4], bfB[4];
#pragma unroll
    for (int m = 0; m < 4; ++m)
      bfA[m] = *(const i32x4*)(Blds + m * 1024 + lane * 16);

#define GBODY(CUR, NXT, g)                                                   \
  {                                                                          \
    const int gn_ = ((g) + 1) & 31;                                          \
    _Pragma("unroll") for (int m = 0; m < 4; ++m)                            \
        NXT[m] = *(const i32x4*)(Blds + gn_ * 4096 + m * 1024 + lane * 16);  \
    const int enk_ = (ens[(g) * 16 + c15] << 8) | (g);                       \
    i32x4 a0 = {0, 0, 0, 0}, a1 = {0, 0, 0, 0};                              \
    i32x4 a2 = {0, 0, 0, 0}, a3 = {0, 0, 0, 0};                              \
    _Pragma("unroll") for (int m = 0; m < 4; ++m) {                          \
      a0 = __builtin_amdgcn_mfma_i32_16x16x64_i8(af[0][m], CUR[m], a0, 0, 0, 0); \
      a1 = __builtin_amdgcn_mfma_i32_16x16x64_i8(af[1][m], CUR[m], a1, 0, 0, 0); \
      a2 = __builtin_amdgcn_mfma_i32_16x16x64_i8(af[2][m], CUR[m], a2, 0, 0, 0); \
      a3 = __builtin_amdgcn_mfma_i32_16x16x64_i8(af[3][m], CUR[m], a3, 0, 0, 0); \
    }                                                                        \
    _Pragma("unroll") for (int r = 0; r < 4; ++r) {                          \
      best[0][r] = min(best[0][r], enk_ - (int)((unsigned)a0[r] << 8));      \
      best[1][r] = min(best[1][r], enk_ - (int)((unsigned)a1[r] << 8));      \
      best[2][r] = min(best[2][r], enk_ - (int)((unsigned)a2[r] << 8));      \
      best[3][r] = min(best[3][r], enk_ - (int)((unsigned)a3[r] << 8));      \
    }                                                                        \
  }

#pragma unroll 1
    for (int gg = 0; gg < 32; gg += 2) {
      GBODY(bfA, bfB, gg);
      GBODY(bfB, bfA, gg + 1);
    }
#undef GBODY

    // reduce over 16 code-lanes (c15), lowest index on ties; write candidate
#pragma unroll
    for (int t = 0; t < 4; ++t)
#pragma unroll
      for (int r = 0; r < 4; ++r) {
        const int key = best[t][r];
        int s = key >> 8;
        int i = slice * 512 + ((key & 255) << 4) + c15;  // g*16 + c15
#pragma unroll
        for (int m = 1; m <= 8; m <<= 1) {
          const int os = __shfl_xor(s, m, 64);
          const int oi = __shfl_xor(i, m, 64);
          if (os < s || (os == s && oi < i)) { s = os; i = oi; }
        }
        if (c15 == 0) {
          const int row = wrow0 + rr * 64 + t * 16 + quad * 4 + r;
          cand[(size_t)row * 16 + slice] =
              ((long long)s << 32) | (unsigned int)i;
        }
      }
  }
}

// ---- merge slices + gather + loss + hist + finalize ----
__global__ __launch_bounds__(256) void vq_epi(
    const float* __restrict__ X, const float* __restrict__ Ef,
    const long long* __restrict__ cand, float* __restrict__ outq,
    double* __restrict__ loss_sum, int* __restrict__ hist,
    unsigned int* __restrict__ ticket, float* __restrict__ out) {
  __shared__ int kfin[64];
  __shared__ double wsum[4];
  __shared__ double part[256];
  __shared__ int sdone;

  const int tid = threadIdx.x;
  const int wave = tid >> 6;
  const int lane = tid & 63;
  const int r0 = blockIdx.x * 64;

  if (tid < 64) {
    const long long* cp = cand + (size_t)(r0 + tid) * 16;
    long long b = cp[0];
#pragma unroll
    for (int sl = 1; sl < 16; ++sl) {
      const long long v = cp[sl];
      b = (v < b) ? v : b;  // lexicographic (score, index) min
    }
    const int bi = (int)(b & 0xffffffffll);
    kfin[tid] = bi;
    __hip_atomic_fetch_add(&hist[bi], 1, __ATOMIC_RELAXED,
                           __HIP_MEMORY_SCOPE_AGENT);
  }
  __syncthreads();

  // fused gather (from f32 E) + loss partial: wave w handles rows w*16..+16
  double lacc = 0.0;
#pragma unroll
  for (int j = 0; j < 16; ++j) {
    const int rl = wave * 16 + j;
    const int k = kfin[rl];
    const float4 q = *(const float4*)(Ef + (size_t)k * VQ_D + lane * 4);
    const float4 x =
        *(const float4*)(X + (size_t)(r0 + rl) * VQ_D + lane * 4);
    *(float4*)(outq + (size_t)(r0 + rl) * VQ_D + lane * 4) = q;
    const double dx = (double)q.x - x.x, dy = (double)q.y - x.y;
    const double dz = (double)q.z - x.z, dw = (double)q.w - x.w;
    lacc += dx * dx + dy * dy + dz * dz + dw * dw;
  }
#pragma unroll
  for (int off = 32; off > 0; off >>= 1) lacc += __shfl_down(lacc, off, 64);
  if (lane == 0) wsum[wave] = lacc;
  __syncthreads();
  if (tid == 0) {
    atomicAdd(loss_sum, wsum[0] + wsum[1] + wsum[2] + wsum[3]);
    __threadfence();
    const unsigned int old = __hip_atomic_fetch_add(
        ticket, 1u, __ATOMIC_ACQ_REL, __HIP_MEMORY_SCOPE_AGENT);
    sdone = (old == 255u) ? 1 : 0;
  }
  __syncthreads();

  if (sdone) {  // last block: all hist/loss atomics are visible
    double s = 0.0;
    for (int k = tid; k < VQ_K; k += 256) {
      const int c = __hip_atomic_load(&hist[k], __ATOMIC_RELAXED,
                                      __HIP_MEMORY_SCOPE_AGENT);
      if (c > 0) {
        const double pr = (double)c * (1.0 / (double)VQ_N);
        s += pr * log(pr + 1e-10);
      }
    }
    part[tid] = s;
    __syncthreads();
    for (int off = 128; off > 0; off >>= 1) {
      if (tid < off) part[tid] += part[tid + off];
      __syncthreads();
    }
    if (tid == 0) {
      const double ls = __hip_atomic_load(loss_sum, __ATOMIC_RELAXED,
                                          __HIP_MEMORY_SCOPE_AGENT);
      out[(size_t)VQ_N * VQ_D] =
          (float)(1.25 * ls / ((double)VQ_N * (double)VQ_D));
      out[(size_t)VQ_N * VQ_D + 1] = (float)exp(-part[0]);
    }
  }
}

extern "C" void kernel_launch(void* const* d_in, const int* in_sizes, int n_in,
                              void* d_out, int out_size, void* d_ws,
                              size_t ws_size, hipStream_t stream) {
  const float* X = (const float*)d_in[0];
  const float* E = (const float*)d_in[1];
  float* out = (float*)d_out;

  char* ws = (char*)d_ws;
  signed char* Ebs = (signed char*)ws;                   // 2 MB   @ 0
  signed char* Xq = (signed char*)(ws + 2097152);        // 4 MB   @ 2M
  int* en_int = (int*)(ws + 6291456);                    // 32 KB
  int* hist = (int*)(ws + 6324224);                      // 32 KB
  double* loss_sum = (double*)(ws + 6356992);            // 64 B
  unsigned int* ticket = (unsigned int*)(ws + 6357056);  // 64 B
  long long* cand = (long long*)(ws + 6357120);          // 2 MB

  vq_pack<<<1536, 256, 0, stream>>>(E, X, Ebs, Xq, en_int, loss_sum, hist,
                                    ticket);
  vq_main<<<256, 256, 0, stream>>>(Ebs, Xq, en_int, cand);
  vq_epi<<<256, 256, 0, stream>>>(X, E, cand, out, loss_sum, hist, ticket,
                                  out);
}